// Round 21
// baseline (454.690 us; speedup 1.0000x reference)
//
#include <hip/hip_runtime.h>
#include <hip/hip_bf16.h>

#define N_NODES 50000
#define N_EDGES 800000
#define MUL0 64
#define MUL1 32
#define D_IN 160      // 64 + 3*32
#define FC_H 64
#define W_NUMEL 192   // 64+64+32+32
#define FEAT 384      // 64 + 32 + 192 + 96
#define ACT_C 1.6791f
#define INV_SQRT3 0.57735026918962576f
#define RSQRT32 0.17677669529663687f
#define RSQRT96 0.10206207261596575f

#define TILE 64
#define NWG_EDGE (N_EDGES / TILE)   // 12500

typedef __attribute__((ext_vector_type(8))) short s16x8;
typedef __attribute__((ext_vector_type(4))) float f32x4;
typedef _Float16 h8 __attribute__((ext_vector_type(8)));
typedef __fp16 fp16x2 __attribute__((ext_vector_type(2)));

static __device__ __forceinline__ unsigned short f2bf(float f) {
    __hip_bfloat16 b = __float2bfloat16(f);
    return __builtin_bit_cast(unsigned short, b);
}

// R10-proven paired-row swizzle for 32-edge sub-tiles.
static __device__ __forceinline__ int swz(int row, int byte_in_row) {
    int unit = ((row & 1) << 2) | (byte_in_row >> 4);
    int su = unit ^ ((row >> 1) & 7);
    return (row >> 1) * 128 + su * 16 + (byte_in_row & 15);
}
static __device__ __forceinline__ h8 rdh8(const unsigned char* base, int row, int eb) {
    return *(const h8*)(base + swz(row, eb));
}

// ---------------- utility kernels ----------------

#define ZERO_NB  18750                              // N*FEAT floats / (256*4)
#define HIST_NB  ((N_EDGES + 255) / 256)            // 3125
#define XCONV_NB ((N_NODES * D_IN + 4095) / 4096)   // 1954

// accg zero + hist + weight prep + x f32->f16 compression (all independent;
// cnt is zeroed by the small preceding memset)
__global__ __launch_bounds__(256) void hist_prep_kernel(
    const int*   __restrict__ eidx,
    int*         __restrict__ cnt,
    float*       __restrict__ accg,
    const float* __restrict__ w_fc1,
    const float* __restrict__ w_fc2,
    const float* __restrict__ w_sc_s,
    const float* __restrict__ w_sc_v,
    const float* __restrict__ w_lin_s,
    const float* __restrict__ w_lin_v,
    const float* __restrict__ x,
    unsigned short* __restrict__ x16,    // N x 160 f16
    unsigned short* __restrict__ w1t,
    unsigned short* __restrict__ w2t,
    unsigned short* __restrict__ wscs_t,
    unsigned short* __restrict__ wscv_t,
    unsigned short* __restrict__ wlins_t,
    unsigned short* __restrict__ wlinv_t)
{
    int b = blockIdx.x;
    if (b < ZERO_NB) {
        size_t i = ((size_t)b * 256 + threadIdx.x) * 4;
        if (i < (size_t)N_NODES * FEAT) {
            float4 z = {0.f, 0.f, 0.f, 0.f};
            *(float4*)(accg + i) = z;
        }
    } else if (b < ZERO_NB + HIST_NB) {
        int e = (b - ZERO_NB) * 256 + threadIdx.x;
        if (e < N_EDGES) atomicAdd(&cnt[eidx[N_EDGES + e]], 1);
    } else if (b < ZERO_NB + HIST_NB + 48) {
        int i = (b - ZERO_NB - HIST_NB) * 256 + threadIdx.x;
        if (i < 64 * 64)  w1t[i]    = f2bf(w_fc1[(i & 63) * FC_H + (i >> 6)]);
        if (i < 192 * 64) w2t[i]    = f2bf(w_fc2[(i & 63) * W_NUMEL + (i >> 6)]);
        if (i < 64 * 64)  wscs_t[i] = f2bf(w_sc_s[(i & 63) * 64 + (i >> 6)]);
        if (i < 32 * 32)  wscv_t[i] = f2bf(w_sc_v[(i & 31) * 32 + (i >> 5)]);
        if (i < 64 * 96)  wlins_t[i] = f2bf(w_lin_s[(i % 96) * 64 + (i / 96)]);
        if (i < 32 * 96)  wlinv_t[i] = f2bf(w_lin_v[(i % 96) * 32 + (i / 96)]);
    } else {
        size_t i0 = ((size_t)(b - ZERO_NB - HIST_NB - 48) * 256 + threadIdx.x) * 16;
        if (i0 < (size_t)N_NODES * D_IN) {
            const float4* src = (const float4*)(x + i0);
            unsigned short u[16];
#pragma unroll
            for (int k = 0; k < 4; ++k) {
                float4 v = src[k];
                u[k * 4 + 0] = __builtin_bit_cast(unsigned short, (_Float16)v.x);
                u[k * 4 + 1] = __builtin_bit_cast(unsigned short, (_Float16)v.y);
                u[k * 4 + 2] = __builtin_bit_cast(unsigned short, (_Float16)v.z);
                u[k * 4 + 3] = __builtin_bit_cast(unsigned short, (_Float16)v.w);
            }
            uint4* dst = (uint4*)(x16 + i0);
            dst[0] = *(const uint4*)&u[0];
            dst[1] = *(const uint4*)&u[8];
        }
    }
}

#define SCAN_NB 64
#define SCAN_CH ((N_NODES + SCAN_NB - 1) / SCAN_NB)   // 782

// single-kernel exclusive scan: each block computes its own global prefix
__global__ __launch_bounds__(256) void scan_kernel(const int* __restrict__ cnt,
                                                   int* __restrict__ fill) {
    __shared__ int s_w[4];
    __shared__ int s_boff;
    int b = blockIdx.x, t = threadIdx.x;
    // global prefix: sum of cnt[0 .. b*SCAN_CH)
    {
        int lim = min(b * SCAN_CH, N_NODES);
        int s = 0;
        for (int i = t; i < lim; i += 256) s += cnt[i];
        for (int d = 1; d < 64; d <<= 1) s += __shfl_xor(s, d);
        if ((t & 63) == 0) s_w[t >> 6] = s;
        __syncthreads();
        if (t == 0) s_boff = s_w[0] + s_w[1] + s_w[2] + s_w[3];
        __syncthreads();
    }
    // own-chunk scan
    const int CH2 = (SCAN_CH + 255) / 256;   // 4
    int base = b * SCAN_CH + t * CH2;
    int lim = min((b + 1) * SCAN_CH, N_NODES);
    int s = 0;
#pragma unroll
    for (int k = 0; k < CH2; ++k) { int i = base + k; if (i < lim) s += cnt[i]; }
    int v = s;
    for (int d = 1; d < 64; d <<= 1) { int u = __shfl_up(v, d); if ((t & 63) >= d) v += u; }
    __syncthreads();   // reuse s_w
    if ((t & 63) == 63) s_w[t >> 6] = v;
    __syncthreads();
    int woff = 0;
#pragma unroll
    for (int w = 0; w < 4; ++w) if (w < (t >> 6)) woff += s_w[w];
    int run = s_boff + woff + (v - s);
#pragma unroll
    for (int k = 0; k < CH2; ++k) {
        int i = base + k;
        if (i < lim) { fill[i] = run; run += cnt[i]; }
    }
}

// sort: also scatters sh into sorted order (removes a random stream from edge)
__global__ __launch_bounds__(256) void scatter_ids_kernel(const int* __restrict__ eidx,
                                                          const float* __restrict__ sh,
                                                          int* __restrict__ fill,
                                                          int* __restrict__ sorted_eid,
                                                          int* __restrict__ sorted_src,
                                                          int* __restrict__ sorted_dst,
                                                          float* __restrict__ shs) {
    int e = blockIdx.x * 256 + threadIdx.x;
    if (e < N_EDGES) {
        int d = eidx[N_EDGES + e];
        int s = eidx[e];
        int p = atomicAdd(&fill[d], 1);
        sorted_eid[p] = e;
        sorted_src[p] = s;
        sorted_dst[p] = d;
        *(float4*)(shs + (size_t)p * 4) = *(const float4*)(sh + (size_t)e * 4);
    }
}

// ---------------- fused edge kernel (TILE=64, f16 x, sorted sh) ----------------
#define X_OFF    0
#define W_OFF    20480
#define SH_OFF   45056
#define SID_OFF  45568
#define SEGN_OFF 45696
#define NSEG_OFF 45952
#define SMEM_SZ  45968

static __device__ __forceinline__ h8 seg_mask(const unsigned* vv, unsigned tgt) {
    h8 a;
#pragma unroll
    for (int w2 = 0; w2 < 4; ++w2) {
        a[w2 * 2]     = ((vv[w2] & 0xffffu) == tgt) ? (_Float16)1.f : (_Float16)0.f;
        a[w2 * 2 + 1] = ((vv[w2] >> 16)     == tgt) ? (_Float16)1.f : (_Float16)0.f;
    }
    return a;
}

__global__ __launch_bounds__(256) void edge_kernel(
    const unsigned short* __restrict__ x16,    // N x 160 f16
    const float* __restrict__ es,
    const float* __restrict__ shs,             // E x 4, sorted
    const int*   __restrict__ sorted_eid,
    const int*   __restrict__ sorted_src,
    const int*   __restrict__ sorted_dst,
    const unsigned short* __restrict__ w1t,
    const unsigned short* __restrict__ w2t,
    float* __restrict__ accg)
{
    __shared__ __align__(16) unsigned char smem[SMEM_SZ];
    int* s_segnode = (int*)(smem + SEGN_OFF);
    unsigned short* s_sid = (unsigned short*)(smem + SID_OFF);

    const int t = threadIdx.x;
    const int l = t & 63;
    const int wv = t >> 6;
    const int lr = l & 15;
    const int lk = l >> 4;
    int bid;
    {
        const int nwg = NWG_EDGE;
        int orig = blockIdx.x;
        int xcd = orig & 7, idx = orig >> 3;
        int q = nwg >> 3, r = nwg & 7;
        bid = (xcd < r ? xcd * (q + 1) : r * (q + 1) + (xcd - r) * q) + idx;
    }
    const int tile0 = bid * TILE;

    // ---- (1) loads: es row (random f32), x16 gather, sh (sequential), ballot ----
    int eid_own = sorted_eid[tile0 + wv * 16 + lr];
    float4 esf[4];
    {
        const float4* ep = (const float4*)(es + (size_t)eid_own * FC_H);
        esf[0] = ep[lk * 2];     esf[1] = ep[lk * 2 + 1];
        esf[2] = ep[8 + lk * 2]; esf[3] = ep[8 + lk * 2 + 1];
    }
    const int hs   = t >> 7;
    const int tt_h = t & 127;
    const int xe   = tt_h & 31;
    const int cgrp = tt_h >> 5;        // 0..3, each covers 5 float4 = 40 f16
    float4 xg[5];
    {
        const float4* xp = (const float4*)(x16 + (size_t)sorted_src[tile0 + hs * 32 + xe] * D_IN);
#pragma unroll
        for (int k = 0; k < 5; ++k) xg[k] = xp[cgrp * 5 + k];
    }
    float shv = shs[(size_t)tile0 * 4 + t];   // fully sequential
    if (wv == 0) {
        int dl = sorted_dst[tile0 + l];
        int nd = __shfl_down(dl, 1);
        bool flag = (l == 63) || (dl != nd);
        unsigned long long m = __ballot(flag);
        int sid = __popcll(m & ((1ull << l) - 1ull));
        s_sid[l] = (unsigned short)sid;
        if (flag) s_segnode[sid] = dl;
        if (l == 63) *(int*)(smem + NSEG_OFF) = sid + 1;
    }

    // ---- (2) layer 1 ----
    unsigned short* s_h = (unsigned short*)(smem + X_OFF);
    s16x8 afrag[2];
    {
        s16x8 a;
        a[0] = f2bf(esf[0].x); a[1] = f2bf(esf[0].y); a[2] = f2bf(esf[0].z); a[3] = f2bf(esf[0].w);
        a[4] = f2bf(esf[1].x); a[5] = f2bf(esf[1].y); a[6] = f2bf(esf[1].z); a[7] = f2bf(esf[1].w);
        afrag[0] = a;
        a[0] = f2bf(esf[2].x); a[1] = f2bf(esf[2].y); a[2] = f2bf(esf[2].z); a[3] = f2bf(esf[2].w);
        a[4] = f2bf(esf[3].x); a[5] = f2bf(esf[3].y); a[6] = f2bf(esf[3].z); a[7] = f2bf(esf[3].w);
        afrag[1] = a;
    }
#pragma unroll
    for (int nt = 0; nt < 4; ++nt) {
        f32x4 hacc = {0.f, 0.f, 0.f, 0.f};
#pragma unroll
        for (int kk = 0; kk < 2; ++kk) {
            s16x8 b = *(const s16x8*)(w1t + (nt * 16 + lr) * 64 + kk * 32 + lk * 8);
            hacc = __builtin_amdgcn_mfma_f32_16x16x32_bf16(afrag[kk], b, hacc, 0, 0, 0);
        }
#pragma unroll
        for (int q = 0; q < 4; ++q) {
            float aa = hacc[q] * 0.125f;
            float hv = aa * (1.f / (1.f + __expf(-aa))) * ACT_C;
            s_h[(wv * 16 + lk * 4 + q) * 72 + nt * 16 + lr] = f2bf(hv);
        }
    }
    s16x8 hfrag[2];
#pragma unroll
    for (int kk = 0; kk < 2; ++kk)
        hfrag[kk] = *(const s16x8*)(s_h + (wv * 16 + lr) * 72 + kk * 32 + lk * 8);
    __syncthreads();   // #A

    // ---- (3) layer 2 -> wT, xT/shT writes ----
    {
        const int ws = wv >> 1;
        const int ebyte = (wv & 1) * 32 + lk * 8;
        unsigned char* bw = smem + W_OFF + ws * 12288;
#pragma unroll
        for (int nt = 0; nt < 12; ++nt) {
            f32x4 acc = {0.f, 0.f, 0.f, 0.f};
#pragma unroll
            for (int kk = 0; kk < 2; ++kk) {
                s16x8 b = *(const s16x8*)(w2t + (nt * 16 + lr) * 64 + kk * 32 + lk * 8);
                acc = __builtin_amdgcn_mfma_f32_16x16x32_bf16(hfrag[kk], b, acc, 0, 0, 0);
            }
            int f = nt * 16 + lr;
            fp16x2 p0 = __builtin_amdgcn_cvt_pkrtz(acc[0] * 0.125f, acc[1] * 0.125f);
            fp16x2 p1 = __builtin_amdgcn_cvt_pkrtz(acc[2] * 0.125f, acc[3] * 0.125f);
            uint2 wval = { __builtin_bit_cast(unsigned, p0), __builtin_bit_cast(unsigned, p1) };
            *(uint2*)(bw + swz(f, ebyte)) = wval;
        }
    }
    {
        unsigned char* bx = smem + X_OFF + hs * 10240;
#pragma unroll
        for (int k = 0; k < 5; ++k) {
            unsigned short u[8];
            *(float4*)u = xg[k];
#pragma unroll
            for (int jj = 0; jj < 8; ++jj) {
                int r = (cgrp * 5 + k) * 8 + jj;
                *(unsigned short*)(bx + swz(r, xe * 2)) = u[jj];
            }
        }
    }
    {
        int e = t >> 2, c = t & 3;
        *(_Float16*)(smem + SH_OFF + (e >> 5) * 256 + swz(c, (e & 31) * 2)) = (_Float16)shv;
    }
    __syncthreads();   // #B

    // ---- (4) phase C ----
    const int nseg = *(const int*)(smem + NSEG_OFF);
    const int eb = lk * 16;

    h8 shreg[4][2];
    unsigned vv[2][4];
#pragma unroll
    for (int ks = 0; ks < 2; ++ks) {
#pragma unroll
        for (int r = 0; r < 4; ++r)
            shreg[r][ks] = rdh8(smem + SH_OFF + ks * 256, r, eb);
        uint4 sv = *(const uint4*)(smem + SID_OFF + ks * 64 + lk * 16);
        vv[ks][0] = sv.x; vv[ks][1] = sv.y; vv[ks][2] = sv.z; vv[ks][3] = sv.w;
    }

    h8 Bv[4][2];
    int fcol[4];
    bool cls3j[4] = {false, false, false, false};
#pragma unroll
    for (int ks = 0; ks < 2; ++ks) {
        const unsigned char* bx = smem + X_OFF + ks * 10240;
        const unsigned char* bw = smem + W_OFF + ks * 12288;
        if (wv == 0) {
#pragma unroll
            for (int jj = 0; jj < 4; ++jj) {
                int col = jj * 16 + lr;
                Bv[jj][ks] = rdh8(bw, col, eb) * rdh8(bx, col, eb);
                fcol[jj] = col;
            }
        } else if (wv == 1) {
#pragma unroll
            for (int jj = 0; jj < 4; ++jj) {
                int col = jj * 16 + lr;
                Bv[jj][ks] = rdh8(bw, 128 + col / 3, eb) * rdh8(bx, 64 + col, eb);
                fcol[jj] = 288 + col;
            }
        } else if (wv == 2) {
#pragma unroll
            for (int jj = 0; jj < 2; ++jj) {
                int col = 64 + jj * 16 + lr;
                Bv[jj][ks] = rdh8(bw, 128 + col / 3, eb) * rdh8(bx, 64 + col, eb);
                fcol[jj] = 288 + col;
            }
#pragma unroll
            for (int jj = 2; jj < 4; ++jj) {
                int col = (jj - 2) * 16 + lr;
                h8 d = rdh8(bx, 64 + 3 * col, eb)     * shreg[1][ks]
                     + rdh8(bx, 64 + 3 * col + 1, eb) * shreg[2][ks]
                     + rdh8(bx, 64 + 3 * col + 2, eb) * shreg[3][ks];
                Bv[jj][ks] = rdh8(bw, 160 + col, eb) * d;
                fcol[jj] = 64 + col;
                cls3j[jj] = true;
            }
        } else {
#pragma unroll
            for (int jj = 0; jj < 4; ++jj) {
                int col = jj * 16 + lr;
                Bv[jj][ks] = rdh8(bw, 64 + col, eb) * rdh8(bx, col, eb);
                fcol[jj] = 96 + 3 * col;
            }
        }
    }

    if (wv != 3) {
        const int npass = (nseg + 15) >> 4;
        for (int p = 0; p < npass; ++p) {
            h8 bm0 = seg_mask(vv[0], (unsigned)(p * 16 + lr));
            h8 bm1 = seg_mask(vv[1], (unsigned)(p * 16 + lr));
            h8 As0 = bm0 * shreg[0][0];
            h8 As1 = bm1 * shreg[0][1];
            const int m0 = p * 16 + lk * 4;
            float* nptr[4]; bool valid[4], atq[4];
#pragma unroll
            for (int q = 0; q < 4; ++q) {
                int sg = m0 + q;
                valid[q] = sg < nseg;
                int node = valid[q] ? s_segnode[sg] : 0;
                nptr[q] = accg + (size_t)node * FEAT;
                atq[q] = (sg == 0) || (sg == nseg - 1);
            }
#pragma unroll
            for (int jj = 0; jj < 4; ++jj) {
                f32x4 acc = {0.f, 0.f, 0.f, 0.f};
                acc = __builtin_amdgcn_mfma_f32_16x16x32_f16(cls3j[jj] ? bm0 : As0, Bv[jj][0], acc, 0, 0, 0);
                acc = __builtin_amdgcn_mfma_f32_16x16x32_f16(cls3j[jj] ? bm1 : As1, Bv[jj][1], acc, 0, 0, 0);
                const float sc = cls3j[jj] ? INV_SQRT3 : 1.f;
#pragma unroll
                for (int q = 0; q < 4; ++q) {
                    if (valid[q]) {
                        float v = acc[q] * sc;
                        float* a = nptr[q] + fcol[jj];
                        if (atq[q]) atomicAdd(a, v); else *a = v;
                    }
                }
            }
        }
    } else {
        const int npass = (3 * nseg + 15) >> 4;
        for (int p = 0; p < npass; ++p) {
            int m = p * 16 + lr;
            int sgA = m / 3, i3A = m - 3 * sgA;
            h8 mk0 = seg_mask(vv[0], (unsigned)sgA);
            h8 mk1 = seg_mask(vv[1], (unsigned)sgA);
            h8 A0 = mk0 * ((i3A == 0) ? shreg[1][0] : (i3A == 1) ? shreg[2][0] : shreg[3][0]);
            h8 A1 = mk1 * ((i3A == 0) ? shreg[1][1] : (i3A == 1) ? shreg[2][1] : shreg[3][1]);
            int m0 = p * 16 + lk * 4;
            int sgq = m0 / 3, rq = m0 - 3 * sgq;
            float* nptr[4]; int i3q[4]; bool valid[4], atq[4];
#pragma unroll
            for (int q = 0; q < 4; ++q) {
                valid[q] = sgq < nseg;
                int node = valid[q] ? s_segnode[sgq] : 0;
                nptr[q] = accg + (size_t)node * FEAT;
                i3q[q] = rq;
                atq[q] = (sgq == 0) || (sgq == nseg - 1);
                if (++rq == 3) { rq = 0; ++sgq; }
            }
#pragma unroll
            for (int jj = 0; jj < 4; ++jj) {
                f32x4 acc = {0.f, 0.f, 0.f, 0.f};
                acc = __builtin_amdgcn_mfma_f32_16x16x32_f16(A0, Bv[jj][0], acc, 0, 0, 0);
                acc = __builtin_amdgcn_mfma_f32_16x16x32_f16(A1, Bv[jj][1], acc, 0, 0, 0);
#pragma unroll
                for (int q = 0; q < 4; ++q) {
                    if (valid[q]) {
                        float* a = nptr[q] + fcol[jj] + i3q[q];
                        if (atq[q]) atomicAdd(a, acc[q]); else *a = acc[q];
                    }
                }
            }
        }
    }
}

// ---------------- node epilogue (MFMA) ----------------

static __device__ __forceinline__ s16x8 frag_c8(const float* p, float s) {
    float4 u = *(const float4*)p, v = *(const float4*)(p + 4);
    s16x8 a;
    a[0] = f2bf(u.x * s); a[1] = f2bf(u.y * s); a[2] = f2bf(u.z * s); a[3] = f2bf(u.w * s);
    a[4] = f2bf(v.x * s); a[5] = f2bf(v.y * s); a[6] = f2bf(v.z * s); a[7] = f2bf(v.w * s);
    return a;
}

__global__ __launch_bounds__(256) void node_kernel(
    const float* __restrict__ x,
    const float* __restrict__ accg,
    const int*   __restrict__ cnt,
    const unsigned short* __restrict__ wscs_t,
    const unsigned short* __restrict__ wscv_t,
    const unsigned short* __restrict__ wlins_t,
    const unsigned short* __restrict__ wlinv_t,
    const float* __restrict__ w_alpha,
    float* __restrict__ out)
{
    const int t = threadIdx.x;
    const int wv = t >> 6, l = t & 63;
    const int lr = l & 15, lk = l >> 4;
    const int n_base = blockIdx.x * 64 + wv * 16;
    const int nrow = n_base + lr;
    const int nclamp = min(nrow, N_NODES - 1);

    const float* mrow = accg + (size_t)nclamp * FEAT;
    const float* xrow = x + (size_t)nclamp * D_IN;
    const float rinv = 1.f / (float)max(cnt[nclamp], 1);

    s16x8 ax[2], ams[3], axv[3], amv[3][3];
#pragma unroll
    for (int kk = 0; kk < 2; ++kk) ax[kk] = frag_c8(xrow + kk * 32 + lk * 8, 1.f);
#pragma unroll
    for (int kk = 0; kk < 3; ++kk) ams[kk] = frag_c8(mrow + kk * 32 + lk * 8, rinv);
    {
        float xb[24];
        const float4* p = (const float4*)(xrow + 64 + 24 * lk);
#pragma unroll
        for (int q = 0; q < 6; ++q) ((float4*)xb)[q] = p[q];
#pragma unroll
        for (int i = 0; i < 3; ++i) {
            s16x8 a;
#pragma unroll
            for (int j = 0; j < 8; ++j) a[j] = f2bf(xb[3 * j + i]);
            axv[i] = a;
        }
    }
#pragma unroll
    for (int kk = 0; kk < 3; ++kk) {
        float mb[24];
        const float4* p = (const float4*)(mrow + 96 + 96 * kk + 24 * lk);
#pragma unroll
        for (int q = 0; q < 6; ++q) ((float4*)mb)[q] = p[q];
#pragma unroll
        for (int i = 0; i < 3; ++i) {
            s16x8 a;
#pragma unroll
            for (int j = 0; j < 8; ++j) a[j] = f2bf(mb[3 * j + i] * rinv);
            amv[i][kk] = a;
        }
    }

    float ap = 0.f;
    {
        float ab[24];
        const float4* p = (const float4*)(mrow + 24 * lk);
#pragma unroll
        for (int q = 0; q < 6; ++q) ((float4*)ab)[q] = p[q];
#pragma unroll
        for (int j = 0; j < 24; ++j) ap += ab[j] * rinv * w_alpha[lk * 24 + j];
    }
    ap += __shfl_xor(ap, 16);
    ap += __shfl_xor(ap, 32);
    const float alphav = ap * RSQRT96;

    f32x4 accA[4], accL[4];
#pragma unroll
    for (int nt = 0; nt < 4; ++nt) { accA[nt] = (f32x4){0,0,0,0}; accL[nt] = (f32x4){0,0,0,0}; }
#pragma unroll
    for (int nt = 0; nt < 4; ++nt) {
#pragma unroll
        for (int kk = 0; kk < 2; ++kk) {
            s16x8 b = *(const s16x8*)(wscs_t + (nt * 16 + lr) * 64 + kk * 32 + lk * 8);
            accA[nt] = __builtin_amdgcn_mfma_f32_16x16x32_bf16(ax[kk], b, accA[nt], 0, 0, 0);
        }
#pragma unroll
        for (int kk = 0; kk < 3; ++kk) {
            s16x8 b = *(const s16x8*)(wlins_t + (nt * 16 + lr) * 96 + kk * 32 + lk * 8);
            accL[nt] = __builtin_amdgcn_mfma_f32_16x16x32_bf16(ams[kk], b, accL[nt], 0, 0, 0);
        }
    }
    f32x4 accVs[3][2], accVl[3][2];
#pragma unroll
    for (int i = 0; i < 3; ++i)
#pragma unroll
        for (int nt = 0; nt < 2; ++nt) { accVs[i][nt] = (f32x4){0,0,0,0}; accVl[i][nt] = (f32x4){0,0,0,0}; }
#pragma unroll
    for (int i = 0; i < 3; ++i) {
#pragma unroll
        for (int nt = 0; nt < 2; ++nt) {
            s16x8 b = *(const s16x8*)(wscv_t + (nt * 16 + lr) * 32 + lk * 8);
            accVs[i][nt] = __builtin_amdgcn_mfma_f32_16x16x32_bf16(axv[i], b, accVs[i][nt], 0, 0, 0);
#pragma unroll
            for (int kk = 0; kk < 3; ++kk) {
                s16x8 b2 = *(const s16x8*)(wlinv_t + (nt * 16 + lr) * 96 + kk * 32 + lk * 8);
                accVl[i][nt] = __builtin_amdgcn_mfma_f32_16x16x32_bf16(amv[i][kk], b2, accVl[i][nt], 0, 0, 0);
            }
        }
    }

#pragma unroll
    for (int q = 0; q < 4; ++q) {
        int row = lk * 4 + q;
        float ar = __shfl(alphav, row);
        int n = n_base + row;
        bool ok = (n < N_NODES);
        float* orow = out + (size_t)n * 160;
#pragma unroll
        for (int nt = 0; nt < 4; ++nt) {
            float vout = accA[nt][q] * 0.125f + ar * accL[nt][q] * RSQRT96;
            if (ok) orow[nt * 16 + lr] = vout;
        }
#pragma unroll
        for (int i = 0; i < 3; ++i)
#pragma unroll
            for (int nt = 0; nt < 2; ++nt) {
                float vout = accVs[i][nt][q] * RSQRT32 + ar * accVl[i][nt][q] * RSQRT96;
                if (ok) orow[64 + 3 * (nt * 16 + lr) + i] = vout;
            }
    }
}

// ---------------- launch ----------------

extern "C" void kernel_launch(void* const* d_in, const int* in_sizes, int n_in,
                              void* d_out, int out_size, void* d_ws, size_t ws_size,
                              hipStream_t stream) {
    const float* x        = (const float*)d_in[0];
    const float* es       = (const float*)d_in[1];
    const float* sh       = (const float*)d_in[2];
    const int*   eidx     = (const int*)d_in[3];
    const float* w_fc1    = (const float*)d_in[4];
    const float* w_fc2    = (const float*)d_in[5];
    const float* w_sc_s   = (const float*)d_in[6];
    const float* w_sc_v   = (const float*)d_in[7];
    const float* w_lin_s  = (const float*)d_in[8];
    const float* w_lin_v  = (const float*)d_in[9];
    const float* w_alpha  = (const float*)d_in[10];
    float* out = (float*)d_out;

    float* accg       = (float*)d_ws;
    int*   cnt        = (int*)(accg + (size_t)N_NODES * FEAT);
    int*   fill       = cnt + N_NODES;
    int*   sorted_eid = fill + N_NODES;
    int*   sorted_src = sorted_eid + N_EDGES;
    int*   sorted_dst = sorted_src + N_EDGES;
    unsigned short* w1t     = (unsigned short*)(sorted_dst + N_EDGES);
    unsigned short* w2t     = w1t + 64 * 64;
    unsigned short* wscs_t  = w2t + 192 * 64;
    unsigned short* wscv_t  = wscs_t + 64 * 64;
    unsigned short* wlins_t = wscv_t + 32 * 32;
    unsigned short* wlinv_t = wlins_t + 64 * 96;
    int* pad = (int*)(wlinv_t + 32 * 96);
    size_t base_bytes = (size_t)((unsigned char*)(pad + SCAN_NB) - (unsigned char*)d_ws);
    base_bytes = (base_bytes + 15) & ~(size_t)15;
    unsigned short* x16 = (unsigned short*)((unsigned char*)d_ws + base_bytes);   // N*160 f16
    float* shs = (float*)(x16 + (size_t)N_NODES * D_IN);                          // E*4 f32

    // zero only cnt (hist order-depends on it); accg zeroed inside hist_prep
    (void)hipMemsetAsync(cnt, 0, (size_t)N_NODES * 4, stream);
    hipLaunchKernelGGL(hist_prep_kernel, dim3(ZERO_NB + HIST_NB + 48 + XCONV_NB), dim3(256), 0, stream,
                       eidx, cnt, accg, w_fc1, w_fc2, w_sc_s, w_sc_v, w_lin_s, w_lin_v,
                       x, x16, w1t, w2t, wscs_t, wscv_t, wlins_t, wlinv_t);
    hipLaunchKernelGGL(scan_kernel, dim3(SCAN_NB), dim3(256), 0, stream, cnt, fill);
    hipLaunchKernelGGL(scatter_ids_kernel, dim3((N_EDGES + 255) / 256), dim3(256), 0, stream,
                       eidx, sh, fill, sorted_eid, sorted_src, sorted_dst, shs);
    hipLaunchKernelGGL(edge_kernel, dim3(NWG_EDGE), dim3(256), 0, stream,
                       x16, es, shs, sorted_eid, sorted_src, sorted_dst, w1t, w2t, accg);
    hipLaunchKernelGGL(node_kernel, dim3((N_NODES + 63) / 64), dim3(256), 0, stream,
                       x, accg, cnt, wscs_t, wscv_t, wlins_t, wlinv_t, w_alpha, out);
}

// Round 22
// 447.154 us; speedup vs baseline: 1.0169x; 1.0169x over previous
//
#include <hip/hip_runtime.h>
#include <hip/hip_bf16.h>

#define N_NODES 50000
#define N_EDGES 800000
#define MUL0 64
#define MUL1 32
#define D_IN 160      // 64 + 3*32
#define FC_H 64
#define W_NUMEL 192   // 64+64+32+32
#define FEAT 384      // 64 + 32 + 192 + 96
#define ACT_C 1.6791f
#define INV_SQRT3 0.57735026918962576f
#define RSQRT32 0.17677669529663687f
#define RSQRT96 0.10206207261596575f

#define TILE 64
#define NWG_EDGE (N_EDGES / TILE)   // 12500

typedef __attribute__((ext_vector_type(8))) short s16x8;
typedef __attribute__((ext_vector_type(4))) float f32x4;
typedef _Float16 h8 __attribute__((ext_vector_type(8)));
typedef __fp16 fp16x2 __attribute__((ext_vector_type(2)));

static __device__ __forceinline__ unsigned short f2bf(float f) {
    __hip_bfloat16 b = __float2bfloat16(f);
    return __builtin_bit_cast(unsigned short, b);
}

// R10-proven paired-row swizzle for 32-edge sub-tiles.
static __device__ __forceinline__ int swz(int row, int byte_in_row) {
    int unit = ((row & 1) << 2) | (byte_in_row >> 4);
    int su = unit ^ ((row >> 1) & 7);
    return (row >> 1) * 128 + su * 16 + (byte_in_row & 15);
}
static __device__ __forceinline__ h8 rdh8(const unsigned char* base, int row, int eb) {
    return *(const h8*)(base + swz(row, eb));
}

// ---------------- utility kernels ----------------

#define HIST_NB  ((N_EDGES + 255) / 256)            // 3125
#define XCONV_NB ((N_NODES * D_IN + 4095) / 4096)   // 1954

// hist + weight prep + x f32->f16 compression (all independent)
__global__ __launch_bounds__(256) void hist_prep_kernel(
    const int*   __restrict__ eidx,
    int*         __restrict__ cnt,
    const float* __restrict__ w_fc1,
    const float* __restrict__ w_fc2,
    const float* __restrict__ w_sc_s,
    const float* __restrict__ w_sc_v,
    const float* __restrict__ w_lin_s,
    const float* __restrict__ w_lin_v,
    const float* __restrict__ x,
    unsigned short* __restrict__ x16,    // N x 160 f16
    unsigned short* __restrict__ w1t,
    unsigned short* __restrict__ w2t,
    unsigned short* __restrict__ wscs_t,
    unsigned short* __restrict__ wscv_t,
    unsigned short* __restrict__ wlins_t,
    unsigned short* __restrict__ wlinv_t)
{
    int b = blockIdx.x;
    if (b < HIST_NB) {
        int e = b * 256 + threadIdx.x;
        if (e < N_EDGES) atomicAdd(&cnt[eidx[N_EDGES + e]], 1);
    } else if (b < HIST_NB + 48) {
        int i = (b - HIST_NB) * 256 + threadIdx.x;
        if (i < 64 * 64)  w1t[i]    = f2bf(w_fc1[(i & 63) * FC_H + (i >> 6)]);
        if (i < 192 * 64) w2t[i]    = f2bf(w_fc2[(i & 63) * W_NUMEL + (i >> 6)]);
        if (i < 64 * 64)  wscs_t[i] = f2bf(w_sc_s[(i & 63) * 64 + (i >> 6)]);
        if (i < 32 * 32)  wscv_t[i] = f2bf(w_sc_v[(i & 31) * 32 + (i >> 5)]);
        if (i < 64 * 96)  wlins_t[i] = f2bf(w_lin_s[(i % 96) * 64 + (i / 96)]);
        if (i < 32 * 96)  wlinv_t[i] = f2bf(w_lin_v[(i % 96) * 32 + (i / 96)]);
    } else {
        // x conversion: 16 elements per thread
        size_t i0 = ((size_t)(b - HIST_NB - 48) * 256 + threadIdx.x) * 16;
        if (i0 < (size_t)N_NODES * D_IN) {
            const float4* src = (const float4*)(x + i0);
            unsigned short u[16];
#pragma unroll
            for (int k = 0; k < 4; ++k) {
                float4 v = src[k];
                u[k * 4 + 0] = __builtin_bit_cast(unsigned short, (_Float16)v.x);
                u[k * 4 + 1] = __builtin_bit_cast(unsigned short, (_Float16)v.y);
                u[k * 4 + 2] = __builtin_bit_cast(unsigned short, (_Float16)v.z);
                u[k * 4 + 3] = __builtin_bit_cast(unsigned short, (_Float16)v.w);
            }
            uint4* dst = (uint4*)(x16 + i0);
            dst[0] = *(const uint4*)&u[0];
            dst[1] = *(const uint4*)&u[8];
        }
    }
}

#define SCAN_NB 64
#define SCAN_CH ((N_NODES + SCAN_NB - 1) / SCAN_NB)   // 782

// single-kernel exclusive scan: each block computes its own global prefix
__global__ __launch_bounds__(256) void scan_kernel(const int* __restrict__ cnt,
                                                   int* __restrict__ fill) {
    __shared__ int s_w[4];
    __shared__ int s_boff;
    int b = blockIdx.x, t = threadIdx.x;
    {
        int lim = min(b * SCAN_CH, N_NODES);
        int s = 0;
        for (int i = t; i < lim; i += 256) s += cnt[i];
        for (int d = 1; d < 64; d <<= 1) s += __shfl_xor(s, d);
        if ((t & 63) == 0) s_w[t >> 6] = s;
        __syncthreads();
        if (t == 0) s_boff = s_w[0] + s_w[1] + s_w[2] + s_w[3];
        __syncthreads();
    }
    const int CH2 = (SCAN_CH + 255) / 256;   // 4
    int base = b * SCAN_CH + t * CH2;
    int lim = min((b + 1) * SCAN_CH, N_NODES);
    int s = 0;
#pragma unroll
    for (int k = 0; k < CH2; ++k) { int i = base + k; if (i < lim) s += cnt[i]; }
    int v = s;
    for (int d = 1; d < 64; d <<= 1) { int u = __shfl_up(v, d); if ((t & 63) >= d) v += u; }
    __syncthreads();
    if ((t & 63) == 63) s_w[t >> 6] = v;
    __syncthreads();
    int woff = 0;
#pragma unroll
    for (int w = 0; w < 4; ++w) if (w < (t >> 6)) woff += s_w[w];
    int run = s_boff + woff + (v - s);
#pragma unroll
    for (int k = 0; k < CH2; ++k) {
        int i = base + k;
        if (i < lim) { fill[i] = run; run += cnt[i]; }
    }
}

__global__ __launch_bounds__(256) void scatter_ids_kernel(const int* __restrict__ eidx,
                                                          int* __restrict__ fill,
                                                          int* __restrict__ sorted_eid,
                                                          int* __restrict__ sorted_src,
                                                          int* __restrict__ sorted_dst) {
    int e = blockIdx.x * 256 + threadIdx.x;
    if (e < N_EDGES) {
        int d = eidx[N_EDGES + e];
        int s = eidx[e];
        int p = atomicAdd(&fill[d], 1);
        sorted_eid[p] = e;
        sorted_src[p] = s;
        sorted_dst[p] = d;
    }
}

// ---------------- fused edge kernel (TILE=64, f16 x) ----------------
#define X_OFF    0
#define W_OFF    20480
#define SH_OFF   45056
#define SID_OFF  45568
#define SEGN_OFF 45696
#define NSEG_OFF 45952
#define SMEM_SZ  45968

static __device__ __forceinline__ h8 seg_mask(const unsigned* vv, unsigned tgt) {
    h8 a;
#pragma unroll
    for (int w2 = 0; w2 < 4; ++w2) {
        a[w2 * 2]     = ((vv[w2] & 0xffffu) == tgt) ? (_Float16)1.f : (_Float16)0.f;
        a[w2 * 2 + 1] = ((vv[w2] >> 16)     == tgt) ? (_Float16)1.f : (_Float16)0.f;
    }
    return a;
}

__global__ __launch_bounds__(256) void edge_kernel(
    const unsigned short* __restrict__ x16,    // N x 160 f16
    const float* __restrict__ es,
    const float* __restrict__ sh,
    const int*   __restrict__ sorted_eid,
    const int*   __restrict__ sorted_src,
    const int*   __restrict__ sorted_dst,
    const unsigned short* __restrict__ w1t,
    const unsigned short* __restrict__ w2t,
    float* __restrict__ accg)
{
    __shared__ __align__(16) unsigned char smem[SMEM_SZ];
    int* s_segnode = (int*)(smem + SEGN_OFF);
    unsigned short* s_sid = (unsigned short*)(smem + SID_OFF);

    const int t = threadIdx.x;
    const int l = t & 63;
    const int wv = t >> 6;
    const int lr = l & 15;
    const int lk = l >> 4;
    int bid;
    {
        const int nwg = NWG_EDGE;
        int orig = blockIdx.x;
        int xcd = orig & 7, idx = orig >> 3;
        int q = nwg >> 3, r = nwg & 7;
        bid = (xcd < r ? xcd * (q + 1) : r * (q + 1) + (xcd - r) * q) + idx;
    }
    const int tile0 = bid * TILE;

    // ---- (1) loads: es row (random f32), x16 gather, sh, ballot ----
    int eid_own = sorted_eid[tile0 + wv * 16 + lr];
    float4 esf[4];
    {
        const float4* ep = (const float4*)(es + (size_t)eid_own * FC_H);
        esf[0] = ep[lk * 2];     esf[1] = ep[lk * 2 + 1];
        esf[2] = ep[8 + lk * 2]; esf[3] = ep[8 + lk * 2 + 1];
    }
    const int hs   = t >> 7;
    const int tt_h = t & 127;
    const int xe   = tt_h & 31;
    const int cgrp = tt_h >> 5;        // 0..3, each covers 5 float4 = 40 f16
    float4 xg[5];
    {
        const float4* xp = (const float4*)(x16 + (size_t)sorted_src[tile0 + hs * 32 + xe] * D_IN);
#pragma unroll
        for (int k = 0; k < 5; ++k) xg[k] = xp[cgrp * 5 + k];
    }
    float shv = sh[(size_t)sorted_eid[tile0 + (t >> 2)] * 4 + (t & 3)];
    if (wv == 0) {
        int dl = sorted_dst[tile0 + l];
        int nd = __shfl_down(dl, 1);
        bool flag = (l == 63) || (dl != nd);
        unsigned long long m = __ballot(flag);
        int sid = __popcll(m & ((1ull << l) - 1ull));
        s_sid[l] = (unsigned short)sid;
        if (flag) s_segnode[sid] = dl;
        if (l == 63) *(int*)(smem + NSEG_OFF) = sid + 1;
    }

    // ---- (2) layer 1 ----
    unsigned short* s_h = (unsigned short*)(smem + X_OFF);
    s16x8 afrag[2];
    {
        s16x8 a;
        a[0] = f2bf(esf[0].x); a[1] = f2bf(esf[0].y); a[2] = f2bf(esf[0].z); a[3] = f2bf(esf[0].w);
        a[4] = f2bf(esf[1].x); a[5] = f2bf(esf[1].y); a[6] = f2bf(esf[1].z); a[7] = f2bf(esf[1].w);
        afrag[0] = a;
        a[0] = f2bf(esf[2].x); a[1] = f2bf(esf[2].y); a[2] = f2bf(esf[2].z); a[3] = f2bf(esf[2].w);
        a[4] = f2bf(esf[3].x); a[5] = f2bf(esf[3].y); a[6] = f2bf(esf[3].z); a[7] = f2bf(esf[3].w);
        afrag[1] = a;
    }
#pragma unroll
    for (int nt = 0; nt < 4; ++nt) {
        f32x4 hacc = {0.f, 0.f, 0.f, 0.f};
#pragma unroll
        for (int kk = 0; kk < 2; ++kk) {
            s16x8 b = *(const s16x8*)(w1t + (nt * 16 + lr) * 64 + kk * 32 + lk * 8);
            hacc = __builtin_amdgcn_mfma_f32_16x16x32_bf16(afrag[kk], b, hacc, 0, 0, 0);
        }
#pragma unroll
        for (int q = 0; q < 4; ++q) {
            float aa = hacc[q] * 0.125f;
            float hv = aa * (1.f / (1.f + __expf(-aa))) * ACT_C;
            s_h[(wv * 16 + lk * 4 + q) * 72 + nt * 16 + lr] = f2bf(hv);
        }
    }
    s16x8 hfrag[2];
#pragma unroll
    for (int kk = 0; kk < 2; ++kk)
        hfrag[kk] = *(const s16x8*)(s_h + (wv * 16 + lr) * 72 + kk * 32 + lk * 8);
    __syncthreads();   // #A

    // ---- (3) layer 2 -> wT, xT/shT writes ----
    {
        const int ws = wv >> 1;
        const int ebyte = (wv & 1) * 32 + lk * 8;
        unsigned char* bw = smem + W_OFF + ws * 12288;
#pragma unroll
        for (int nt = 0; nt < 12; ++nt) {
            f32x4 acc = {0.f, 0.f, 0.f, 0.f};
#pragma unroll
            for (int kk = 0; kk < 2; ++kk) {
                s16x8 b = *(const s16x8*)(w2t + (nt * 16 + lr) * 64 + kk * 32 + lk * 8);
                acc = __builtin_amdgcn_mfma_f32_16x16x32_bf16(hfrag[kk], b, acc, 0, 0, 0);
            }
            int f = nt * 16 + lr;
            fp16x2 p0 = __builtin_amdgcn_cvt_pkrtz(acc[0] * 0.125f, acc[1] * 0.125f);
            fp16x2 p1 = __builtin_amdgcn_cvt_pkrtz(acc[2] * 0.125f, acc[3] * 0.125f);
            uint2 wval = { __builtin_bit_cast(unsigned, p0), __builtin_bit_cast(unsigned, p1) };
            *(uint2*)(bw + swz(f, ebyte)) = wval;
        }
    }
    {
        unsigned char* bx = smem + X_OFF + hs * 10240;
#pragma unroll
        for (int k = 0; k < 5; ++k) {
            unsigned short u[8];
            *(float4*)u = xg[k];
#pragma unroll
            for (int jj = 0; jj < 8; ++jj) {
                int r = (cgrp * 5 + k) * 8 + jj;
                *(unsigned short*)(bx + swz(r, xe * 2)) = u[jj];
            }
        }
    }
    {
        int e = t >> 2, c = t & 3;
        *(_Float16*)(smem + SH_OFF + (e >> 5) * 256 + swz(c, (e & 31) * 2)) = (_Float16)shv;
    }
    __syncthreads();   // #B

    // ---- (4) phase C ----
    const int nseg = *(const int*)(smem + NSEG_OFF);
    const int eb = lk * 16;

    h8 shreg[4][2];
    unsigned vv[2][4];
#pragma unroll
    for (int ks = 0; ks < 2; ++ks) {
#pragma unroll
        for (int r = 0; r < 4; ++r)
            shreg[r][ks] = rdh8(smem + SH_OFF + ks * 256, r, eb);
        uint4 sv = *(const uint4*)(smem + SID_OFF + ks * 64 + lk * 16);
        vv[ks][0] = sv.x; vv[ks][1] = sv.y; vv[ks][2] = sv.z; vv[ks][3] = sv.w;
    }

    h8 Bv[4][2];
    int fcol[4];
    bool cls3j[4] = {false, false, false, false};
#pragma unroll
    for (int ks = 0; ks < 2; ++ks) {
        const unsigned char* bx = smem + X_OFF + ks * 10240;
        const unsigned char* bw = smem + W_OFF + ks * 12288;
        if (wv == 0) {
#pragma unroll
            for (int jj = 0; jj < 4; ++jj) {
                int col = jj * 16 + lr;
                Bv[jj][ks] = rdh8(bw, col, eb) * rdh8(bx, col, eb);
                fcol[jj] = col;
            }
        } else if (wv == 1) {
#pragma unroll
            for (int jj = 0; jj < 4; ++jj) {
                int col = jj * 16 + lr;
                Bv[jj][ks] = rdh8(bw, 128 + col / 3, eb) * rdh8(bx, 64 + col, eb);
                fcol[jj] = 288 + col;
            }
        } else if (wv == 2) {
#pragma unroll
            for (int jj = 0; jj < 2; ++jj) {
                int col = 64 + jj * 16 + lr;
                Bv[jj][ks] = rdh8(bw, 128 + col / 3, eb) * rdh8(bx, 64 + col, eb);
                fcol[jj] = 288 + col;
            }
#pragma unroll
            for (int jj = 2; jj < 4; ++jj) {
                int col = (jj - 2) * 16 + lr;
                h8 d = rdh8(bx, 64 + 3 * col, eb)     * shreg[1][ks]
                     + rdh8(bx, 64 + 3 * col + 1, eb) * shreg[2][ks]
                     + rdh8(bx, 64 + 3 * col + 2, eb) * shreg[3][ks];
                Bv[jj][ks] = rdh8(bw, 160 + col, eb) * d;
                fcol[jj] = 64 + col;
                cls3j[jj] = true;
            }
        } else {
#pragma unroll
            for (int jj = 0; jj < 4; ++jj) {
                int col = jj * 16 + lr;
                Bv[jj][ks] = rdh8(bw, 64 + col, eb) * rdh8(bx, col, eb);
                fcol[jj] = 96 + 3 * col;
            }
        }
    }

    if (wv != 3) {
        const int npass = (nseg + 15) >> 4;
        for (int p = 0; p < npass; ++p) {
            h8 bm0 = seg_mask(vv[0], (unsigned)(p * 16 + lr));
            h8 bm1 = seg_mask(vv[1], (unsigned)(p * 16 + lr));
            h8 As0 = bm0 * shreg[0][0];
            h8 As1 = bm1 * shreg[0][1];
            const int m0 = p * 16 + lk * 4;
            float* nptr[4]; bool valid[4], atq[4];
#pragma unroll
            for (int q = 0; q < 4; ++q) {
                int sg = m0 + q;
                valid[q] = sg < nseg;
                int node = valid[q] ? s_segnode[sg] : 0;
                nptr[q] = accg + (size_t)node * FEAT;
                atq[q] = (sg == 0) || (sg == nseg - 1);
            }
#pragma unroll
            for (int jj = 0; jj < 4; ++jj) {
                f32x4 acc = {0.f, 0.f, 0.f, 0.f};
                acc = __builtin_amdgcn_mfma_f32_16x16x32_f16(cls3j[jj] ? bm0 : As0, Bv[jj][0], acc, 0, 0, 0);
                acc = __builtin_amdgcn_mfma_f32_16x16x32_f16(cls3j[jj] ? bm1 : As1, Bv[jj][1], acc, 0, 0, 0);
                const float sc = cls3j[jj] ? INV_SQRT3 : 1.f;
#pragma unroll
                for (int q = 0; q < 4; ++q) {
                    if (valid[q]) {
                        float v = acc[q] * sc;
                        float* a = nptr[q] + fcol[jj];
                        if (atq[q]) atomicAdd(a, v); else *a = v;
                    }
                }
            }
        }
    } else {
        const int npass = (3 * nseg + 15) >> 4;
        for (int p = 0; p < npass; ++p) {
            int m = p * 16 + lr;
            int sgA = m / 3, i3A = m - 3 * sgA;
            h8 mk0 = seg_mask(vv[0], (unsigned)sgA);
            h8 mk1 = seg_mask(vv[1], (unsigned)sgA);
            h8 A0 = mk0 * ((i3A == 0) ? shreg[1][0] : (i3A == 1) ? shreg[2][0] : shreg[3][0]);
            h8 A1 = mk1 * ((i3A == 0) ? shreg[1][1] : (i3A == 1) ? shreg[2][1] : shreg[3][1]);
            int m0 = p * 16 + lk * 4;
            int sgq = m0 / 3, rq = m0 - 3 * sgq;
            float* nptr[4]; int i3q[4]; bool valid[4], atq[4];
#pragma unroll
            for (int q = 0; q < 4; ++q) {
                valid[q] = sgq < nseg;
                int node = valid[q] ? s_segnode[sgq] : 0;
                nptr[q] = accg + (size_t)node * FEAT;
                i3q[q] = rq;
                atq[q] = (sgq == 0) || (sgq == nseg - 1);
                if (++rq == 3) { rq = 0; ++sgq; }
            }
#pragma unroll
            for (int jj = 0; jj < 4; ++jj) {
                f32x4 acc = {0.f, 0.f, 0.f, 0.f};
                acc = __builtin_amdgcn_mfma_f32_16x16x32_f16(A0, Bv[jj][0], acc, 0, 0, 0);
                acc = __builtin_amdgcn_mfma_f32_16x16x32_f16(A1, Bv[jj][1], acc, 0, 0, 0);
#pragma unroll
                for (int q = 0; q < 4; ++q) {
                    if (valid[q]) {
                        float* a = nptr[q] + fcol[jj] + i3q[q];
                        if (atq[q]) atomicAdd(a, acc[q]); else *a = acc[q];
                    }
                }
            }
        }
    }
}

// ---------------- node epilogue (MFMA) ----------------

static __device__ __forceinline__ s16x8 frag_c8(const float* p, float s) {
    float4 u = *(const float4*)p, v = *(const float4*)(p + 4);
    s16x8 a;
    a[0] = f2bf(u.x * s); a[1] = f2bf(u.y * s); a[2] = f2bf(u.z * s); a[3] = f2bf(u.w * s);
    a[4] = f2bf(v.x * s); a[5] = f2bf(v.y * s); a[6] = f2bf(v.z * s); a[7] = f2bf(v.w * s);
    return a;
}

__global__ __launch_bounds__(256) void node_kernel(
    const float* __restrict__ x,
    const float* __restrict__ accg,
    const int*   __restrict__ cnt,
    const unsigned short* __restrict__ wscs_t,
    const unsigned short* __restrict__ wscv_t,
    const unsigned short* __restrict__ wlins_t,
    const unsigned short* __restrict__ wlinv_t,
    const float* __restrict__ w_alpha,
    float* __restrict__ out)
{
    const int t = threadIdx.x;
    const int wv = t >> 6, l = t & 63;
    const int lr = l & 15, lk = l >> 4;
    const int n_base = blockIdx.x * 64 + wv * 16;
    const int nrow = n_base + lr;
    const int nclamp = min(nrow, N_NODES - 1);

    const float* mrow = accg + (size_t)nclamp * FEAT;
    const float* xrow = x + (size_t)nclamp * D_IN;
    const float rinv = 1.f / (float)max(cnt[nclamp], 1);

    s16x8 ax[2], ams[3], axv[3], amv[3][3];
#pragma unroll
    for (int kk = 0; kk < 2; ++kk) ax[kk] = frag_c8(xrow + kk * 32 + lk * 8, 1.f);
#pragma unroll
    for (int kk = 0; kk < 3; ++kk) ams[kk] = frag_c8(mrow + kk * 32 + lk * 8, rinv);
    {
        float xb[24];
        const float4* p = (const float4*)(xrow + 64 + 24 * lk);
#pragma unroll
        for (int q = 0; q < 6; ++q) ((float4*)xb)[q] = p[q];
#pragma unroll
        for (int i = 0; i < 3; ++i) {
            s16x8 a;
#pragma unroll
            for (int j = 0; j < 8; ++j) a[j] = f2bf(xb[3 * j + i]);
            axv[i] = a;
        }
    }
#pragma unroll
    for (int kk = 0; kk < 3; ++kk) {
        float mb[24];
        const float4* p = (const float4*)(mrow + 96 + 96 * kk + 24 * lk);
#pragma unroll
        for (int q = 0; q < 6; ++q) ((float4*)mb)[q] = p[q];
#pragma unroll
        for (int i = 0; i < 3; ++i) {
            s16x8 a;
#pragma unroll
            for (int j = 0; j < 8; ++j) a[j] = f2bf(mb[3 * j + i] * rinv);
            amv[i][kk] = a;
        }
    }

    float ap = 0.f;
    {
        float ab[24];
        const float4* p = (const float4*)(mrow + 24 * lk);
#pragma unroll
        for (int q = 0; q < 6; ++q) ((float4*)ab)[q] = p[q];
#pragma unroll
        for (int j = 0; j < 24; ++j) ap += ab[j] * rinv * w_alpha[lk * 24 + j];
    }
    ap += __shfl_xor(ap, 16);
    ap += __shfl_xor(ap, 32);
    const float alphav = ap * RSQRT96;

    f32x4 accA[4], accL[4];
#pragma unroll
    for (int nt = 0; nt < 4; ++nt) { accA[nt] = (f32x4){0,0,0,0}; accL[nt] = (f32x4){0,0,0,0}; }
#pragma unroll
    for (int nt = 0; nt < 4; ++nt) {
#pragma unroll
        for (int kk = 0; kk < 2; ++kk) {
            s16x8 b = *(const s16x8*)(wscs_t + (nt * 16 + lr) * 64 + kk * 32 + lk * 8);
            accA[nt] = __builtin_amdgcn_mfma_f32_16x16x32_bf16(ax[kk], b, accA[nt], 0, 0, 0);
        }
#pragma unroll
        for (int kk = 0; kk < 3; ++kk) {
            s16x8 b = *(const s16x8*)(wlins_t + (nt * 16 + lr) * 96 + kk * 32 + lk * 8);
            accL[nt] = __builtin_amdgcn_mfma_f32_16x16x32_bf16(ams[kk], b, accL[nt], 0, 0, 0);
        }
    }
    f32x4 accVs[3][2], accVl[3][2];
#pragma unroll
    for (int i = 0; i < 3; ++i)
#pragma unroll
        for (int nt = 0; nt < 2; ++nt) { accVs[i][nt] = (f32x4){0,0,0,0}; accVl[i][nt] = (f32x4){0,0,0,0}; }
#pragma unroll
    for (int i = 0; i < 3; ++i) {
#pragma unroll
        for (int nt = 0; nt < 2; ++nt) {
            s16x8 b = *(const s16x8*)(wscv_t + (nt * 16 + lr) * 32 + lk * 8);
            accVs[i][nt] = __builtin_amdgcn_mfma_f32_16x16x32_bf16(axv[i], b, accVs[i][nt], 0, 0, 0);
#pragma unroll
            for (int kk = 0; kk < 3; ++kk) {
                s16x8 b2 = *(const s16x8*)(wlinv_t + (nt * 16 + lr) * 96 + kk * 32 + lk * 8);
                accVl[i][nt] = __builtin_amdgcn_mfma_f32_16x16x32_bf16(amv[i][kk], b2, accVl[i][nt], 0, 0, 0);
            }
        }
    }

#pragma unroll
    for (int q = 0; q < 4; ++q) {
        int row = lk * 4 + q;
        float ar = __shfl(alphav, row);
        int n = n_base + row;
        bool ok = (n < N_NODES);
        float* orow = out + (size_t)n * 160;
#pragma unroll
        for (int nt = 0; nt < 4; ++nt) {
            float vout = accA[nt][q] * 0.125f + ar * accL[nt][q] * RSQRT96;
            if (ok) orow[nt * 16 + lr] = vout;
        }
#pragma unroll
        for (int i = 0; i < 3; ++i)
#pragma unroll
            for (int nt = 0; nt < 2; ++nt) {
                float vout = accVs[i][nt][q] * RSQRT32 + ar * accVl[i][nt][q] * RSQRT96;
                if (ok) orow[64 + 3 * (nt * 16 + lr) + i] = vout;
            }
    }
}

// ---------------- launch ----------------

extern "C" void kernel_launch(void* const* d_in, const int* in_sizes, int n_in,
                              void* d_out, int out_size, void* d_ws, size_t ws_size,
                              hipStream_t stream) {
    const float* x        = (const float*)d_in[0];
    const float* es       = (const float*)d_in[1];
    const float* sh       = (const float*)d_in[2];
    const int*   eidx     = (const int*)d_in[3];
    const float* w_fc1    = (const float*)d_in[4];
    const float* w_fc2    = (const float*)d_in[5];
    const float* w_sc_s   = (const float*)d_in[6];
    const float* w_sc_v   = (const float*)d_in[7];
    const float* w_lin_s  = (const float*)d_in[8];
    const float* w_lin_v  = (const float*)d_in[9];
    const float* w_alpha  = (const float*)d_in[10];
    float* out = (float*)d_out;

    float* accg       = (float*)d_ws;
    int*   cnt        = (int*)(accg + (size_t)N_NODES * FEAT);
    int*   fill       = cnt + N_NODES;
    int*   sorted_eid = fill + N_NODES;
    int*   sorted_src = sorted_eid + N_EDGES;
    int*   sorted_dst = sorted_src + N_EDGES;
    unsigned short* w1t     = (unsigned short*)(sorted_dst + N_EDGES);
    unsigned short* w2t     = w1t + 64 * 64;
    unsigned short* wscs_t  = w2t + 192 * 64;
    unsigned short* wscv_t  = wscs_t + 64 * 64;
    unsigned short* wlins_t = wscv_t + 32 * 32;
    unsigned short* wlinv_t = wlins_t + 64 * 96;
    int* pad = (int*)(wlinv_t + 32 * 96);
    size_t base_bytes = (size_t)((unsigned char*)(pad + SCAN_NB) - (unsigned char*)d_ws);
    base_bytes = (base_bytes + 15) & ~(size_t)15;
    unsigned short* x16 = (unsigned short*)((unsigned char*)d_ws + base_bytes);   // N*160 f16

    (void)hipMemsetAsync(d_ws, 0, ((size_t)N_NODES * FEAT + N_NODES) * 4, stream);
    hipLaunchKernelGGL(hist_prep_kernel, dim3(HIST_NB + 48 + XCONV_NB), dim3(256), 0, stream,
                       eidx, cnt, w_fc1, w_fc2, w_sc_s, w_sc_v, w_lin_s, w_lin_v,
                       x, x16, w1t, w2t, wscs_t, wscv_t, wlins_t, wlinv_t);
    hipLaunchKernelGGL(scan_kernel, dim3(SCAN_NB), dim3(256), 0, stream, cnt, fill);
    hipLaunchKernelGGL(scatter_ids_kernel, dim3((N_EDGES + 255) / 256), dim3(256), 0, stream,
                       eidx, fill, sorted_eid, sorted_src, sorted_dst);
    hipLaunchKernelGGL(edge_kernel, dim3(NWG_EDGE), dim3(256), 0, stream,
                       x16, es, sh, sorted_eid, sorted_src, sorted_dst, w1t, w2t, accg);
    hipLaunchKernelGGL(node_kernel, dim3((N_NODES + 63) / 64), dim3(256), 0, stream,
                       x, accg, cnt, wscs_t, wscv_t, wlins_t, wlinv_t, w_alpha, out);
}

// Round 23
// 426.511 us; speedup vs baseline: 1.0661x; 1.0484x over previous
//
#include <hip/hip_runtime.h>
#include <hip/hip_bf16.h>

#define N_NODES 50000
#define N_EDGES 800000
#define MUL0 64
#define MUL1 32
#define D_IN 160      // 64 + 3*32
#define FC_H 64
#define W_NUMEL 192   // 64+64+32+32
#define FEAT 384      // 64 + 32 + 192 + 96
#define ACT_C 1.6791f
#define INV_SQRT3 0.57735026918962576f
#define RSQRT32 0.17677669529663687f
#define RSQRT96 0.10206207261596575f

#define TILE 64
#define NWG_EDGE (N_EDGES / TILE)   // 12500

typedef __attribute__((ext_vector_type(8))) short s16x8;
typedef __attribute__((ext_vector_type(4))) float f32x4;
typedef _Float16 h8 __attribute__((ext_vector_type(8)));
typedef __fp16 fp16x2 __attribute__((ext_vector_type(2)));

static __device__ __forceinline__ unsigned short f2bf(float f) {
    __hip_bfloat16 b = __float2bfloat16(f);
    return __builtin_bit_cast(unsigned short, b);
}

// R10-proven paired-row swizzle for 32-edge sub-tiles.
static __device__ __forceinline__ int swz(int row, int byte_in_row) {
    int unit = ((row & 1) << 2) | (byte_in_row >> 4);
    int su = unit ^ ((row >> 1) & 7);
    return (row >> 1) * 128 + su * 16 + (byte_in_row & 15);
}
static __device__ __forceinline__ h8 rdh8(const unsigned char* base, int row, int eb) {
    return *(const h8*)(base + swz(row, eb));
}

// ---------------- utility kernels ----------------

#define HIST_NB  ((N_EDGES + 255) / 256)            // 3125
#define XCONV_NB ((N_NODES * D_IN + 4095) / 4096)   // 1954

// hist + weight prep + x f32->f16 compression (all independent)
__global__ __launch_bounds__(256) void hist_prep_kernel(
    const int*   __restrict__ eidx,
    int*         __restrict__ cnt,
    const float* __restrict__ w_fc1,
    const float* __restrict__ w_fc2,
    const float* __restrict__ w_sc_s,
    const float* __restrict__ w_sc_v,
    const float* __restrict__ w_lin_s,
    const float* __restrict__ w_lin_v,
    const float* __restrict__ x,
    unsigned short* __restrict__ x16,    // N x 160 f16
    unsigned short* __restrict__ w1t,
    unsigned short* __restrict__ w2t,
    unsigned short* __restrict__ wscs_t,
    unsigned short* __restrict__ wscv_t,
    unsigned short* __restrict__ wlins_t,
    unsigned short* __restrict__ wlinv_t)
{
    int b = blockIdx.x;
    if (b < HIST_NB) {
        int e = b * 256 + threadIdx.x;
        if (e < N_EDGES) atomicAdd(&cnt[eidx[N_EDGES + e]], 1);
    } else if (b < HIST_NB + 48) {
        int i = (b - HIST_NB) * 256 + threadIdx.x;
        if (i < 64 * 64)  w1t[i]    = f2bf(w_fc1[(i & 63) * FC_H + (i >> 6)]);
        if (i < 192 * 64) w2t[i]    = f2bf(w_fc2[(i & 63) * W_NUMEL + (i >> 6)]);
        if (i < 64 * 64)  wscs_t[i] = f2bf(w_sc_s[(i & 63) * 64 + (i >> 6)]);
        if (i < 32 * 32)  wscv_t[i] = f2bf(w_sc_v[(i & 31) * 32 + (i >> 5)]);
        if (i < 64 * 96)  wlins_t[i] = f2bf(w_lin_s[(i % 96) * 64 + (i / 96)]);
        if (i < 32 * 96)  wlinv_t[i] = f2bf(w_lin_v[(i % 96) * 32 + (i / 96)]);
    } else {
        // x conversion: 16 elements per thread
        size_t i0 = ((size_t)(b - HIST_NB - 48) * 256 + threadIdx.x) * 16;
        if (i0 < (size_t)N_NODES * D_IN) {
            const float4* src = (const float4*)(x + i0);
            unsigned short u[16];
#pragma unroll
            for (int k = 0; k < 4; ++k) {
                float4 v = src[k];
                u[k * 4 + 0] = __builtin_bit_cast(unsigned short, (_Float16)v.x);
                u[k * 4 + 1] = __builtin_bit_cast(unsigned short, (_Float16)v.y);
                u[k * 4 + 2] = __builtin_bit_cast(unsigned short, (_Float16)v.z);
                u[k * 4 + 3] = __builtin_bit_cast(unsigned short, (_Float16)v.w);
            }
            uint4* dst = (uint4*)(x16 + i0);
            dst[0] = *(const uint4*)&u[0];
            dst[1] = *(const uint4*)&u[8];
        }
    }
}

#define SCAN_NB 64
#define SCAN_CH ((N_NODES + SCAN_NB - 1) / SCAN_NB)   // 782

__global__ __launch_bounds__(256) void scanA_kernel(const int* __restrict__ cnt,
                                                    int* __restrict__ bsum) {
    __shared__ int sred[4];
    int b = blockIdx.x, t = threadIdx.x;
    int lim = min((b + 1) * SCAN_CH, N_NODES);
    int s = 0;
    for (int i = b * SCAN_CH + t; i < lim; i += 256) s += cnt[i];
    for (int d = 1; d < 64; d <<= 1) s += __shfl_xor(s, d);
    if ((t & 63) == 0) sred[t >> 6] = s;
    __syncthreads();
    if (t == 0) bsum[b] = sred[0] + sred[1] + sred[2] + sred[3];
}

__global__ __launch_bounds__(256) void scanC_kernel(const int* __restrict__ cnt,
                                                    const int* __restrict__ bsum,
                                                    int* __restrict__ fill) {
    __shared__ int s_w[4];
    __shared__ int s_boff;
    int b = blockIdx.x, t = threadIdx.x;
    if (t < 64) {
        int v = bsum[t];
        int p = v;
        for (int d = 1; d < 64; d <<= 1) { int u = __shfl_up(p, d); if (t >= d) p += u; }
        if (t == b) s_boff = p - v;
    }
    const int CH2 = (SCAN_CH + 255) / 256;   // 4
    int base = b * SCAN_CH + t * CH2;
    int lim = min((b + 1) * SCAN_CH, N_NODES);
    int s = 0;
#pragma unroll
    for (int k = 0; k < CH2; ++k) { int i = base + k; if (i < lim) s += cnt[i]; }
    int v = s;
    for (int d = 1; d < 64; d <<= 1) { int u = __shfl_up(v, d); if ((t & 63) >= d) v += u; }
    if ((t & 63) == 63) s_w[t >> 6] = v;
    __syncthreads();
    if (t == 0) { int run = 0; for (int w = 0; w < 4; ++w) { int tv = s_w[w]; s_w[w] = run; run += tv; } }
    __syncthreads();
    int run = s_boff + s_w[t >> 6] + (v - s);
#pragma unroll
    for (int k = 0; k < CH2; ++k) {
        int i = base + k;
        if (i < lim) { fill[i] = run; run += cnt[i]; }
    }
}

__global__ __launch_bounds__(256) void scatter_ids_kernel(const int* __restrict__ eidx,
                                                          int* __restrict__ fill,
                                                          int* __restrict__ sorted_eid,
                                                          int* __restrict__ sorted_src,
                                                          int* __restrict__ sorted_dst) {
    int e = blockIdx.x * 256 + threadIdx.x;
    if (e < N_EDGES) {
        int d = eidx[N_EDGES + e];
        int s = eidx[e];
        int p = atomicAdd(&fill[d], 1);
        sorted_eid[p] = e;
        sorted_src[p] = s;
        sorted_dst[p] = d;
    }
}

// ---------------- fused edge kernel (TILE=64, f16 x) ----------------
#define X_OFF    0
#define W_OFF    20480
#define SH_OFF   45056
#define SID_OFF  45568
#define SEGN_OFF 45696
#define NSEG_OFF 45952
#define SMEM_SZ  45968

static __device__ __forceinline__ h8 seg_mask(const unsigned* vv, unsigned tgt) {
    h8 a;
#pragma unroll
    for (int w2 = 0; w2 < 4; ++w2) {
        a[w2 * 2]     = ((vv[w2] & 0xffffu) == tgt) ? (_Float16)1.f : (_Float16)0.f;
        a[w2 * 2 + 1] = ((vv[w2] >> 16)     == tgt) ? (_Float16)1.f : (_Float16)0.f;
    }
    return a;
}

__global__ __launch_bounds__(256) void edge_kernel(
    const unsigned short* __restrict__ x16,    // N x 160 f16
    const float* __restrict__ es,
    const float* __restrict__ sh,
    const int*   __restrict__ sorted_eid,
    const int*   __restrict__ sorted_src,
    const int*   __restrict__ sorted_dst,
    const unsigned short* __restrict__ w1t,
    const unsigned short* __restrict__ w2t,
    float* __restrict__ accg)
{
    __shared__ __align__(16) unsigned char smem[SMEM_SZ];
    int* s_segnode = (int*)(smem + SEGN_OFF);
    unsigned short* s_sid = (unsigned short*)(smem + SID_OFF);

    const int t = threadIdx.x;
    const int l = t & 63;
    const int wv = t >> 6;
    const int lr = l & 15;
    const int lk = l >> 4;
    int bid;
    {
        const int nwg = NWG_EDGE;
        int orig = blockIdx.x;
        int xcd = orig & 7, idx = orig >> 3;
        int q = nwg >> 3, r = nwg & 7;
        bid = (xcd < r ? xcd * (q + 1) : r * (q + 1) + (xcd - r) * q) + idx;
    }
    const int tile0 = bid * TILE;

    // ---- (1) loads: es row (random f32), x16 gather, sh, ballot ----
    int eid_own = sorted_eid[tile0 + wv * 16 + lr];
    float4 esf[4];
    {
        const float4* ep = (const float4*)(es + (size_t)eid_own * FC_H);
        esf[0] = ep[lk * 2];     esf[1] = ep[lk * 2 + 1];
        esf[2] = ep[8 + lk * 2]; esf[3] = ep[8 + lk * 2 + 1];
    }
    const int hs   = t >> 7;
    const int tt_h = t & 127;
    const int xe   = tt_h & 31;
    const int cgrp = tt_h >> 5;        // 0..3, each covers 5 float4 = 40 f16
    float4 xg[5];
    {
        const float4* xp = (const float4*)(x16 + (size_t)sorted_src[tile0 + hs * 32 + xe] * D_IN);
#pragma unroll
        for (int k = 0; k < 5; ++k) xg[k] = xp[cgrp * 5 + k];
    }
    float shv = sh[(size_t)sorted_eid[tile0 + (t >> 2)] * 4 + (t & 3)];
    if (wv == 0) {
        int dl = sorted_dst[tile0 + l];
        int nd = __shfl_down(dl, 1);
        bool flag = (l == 63) || (dl != nd);
        unsigned long long m = __ballot(flag);
        int sid = __popcll(m & ((1ull << l) - 1ull));
        s_sid[l] = (unsigned short)sid;
        if (flag) s_segnode[sid] = dl;
        if (l == 63) *(int*)(smem + NSEG_OFF) = sid + 1;
    }

    // ---- (2) layer 1 ----
    unsigned short* s_h = (unsigned short*)(smem + X_OFF);
    s16x8 afrag[2];
    {
        s16x8 a;
        a[0] = f2bf(esf[0].x); a[1] = f2bf(esf[0].y); a[2] = f2bf(esf[0].z); a[3] = f2bf(esf[0].w);
        a[4] = f2bf(esf[1].x); a[5] = f2bf(esf[1].y); a[6] = f2bf(esf[1].z); a[7] = f2bf(esf[1].w);
        afrag[0] = a;
        a[0] = f2bf(esf[2].x); a[1] = f2bf(esf[2].y); a[2] = f2bf(esf[2].z); a[3] = f2bf(esf[2].w);
        a[4] = f2bf(esf[3].x); a[5] = f2bf(esf[3].y); a[6] = f2bf(esf[3].z); a[7] = f2bf(esf[3].w);
        afrag[1] = a;
    }
#pragma unroll
    for (int nt = 0; nt < 4; ++nt) {
        f32x4 hacc = {0.f, 0.f, 0.f, 0.f};
#pragma unroll
        for (int kk = 0; kk < 2; ++kk) {
            s16x8 b = *(const s16x8*)(w1t + (nt * 16 + lr) * 64 + kk * 32 + lk * 8);
            hacc = __builtin_amdgcn_mfma_f32_16x16x32_bf16(afrag[kk], b, hacc, 0, 0, 0);
        }
#pragma unroll
        for (int q = 0; q < 4; ++q) {
            float aa = hacc[q] * 0.125f;
            float hv = aa * (1.f / (1.f + __expf(-aa))) * ACT_C;
            s_h[(wv * 16 + lk * 4 + q) * 72 + nt * 16 + lr] = f2bf(hv);
        }
    }
    s16x8 hfrag[2];
#pragma unroll
    for (int kk = 0; kk < 2; ++kk)
        hfrag[kk] = *(const s16x8*)(s_h + (wv * 16 + lr) * 72 + kk * 32 + lk * 8);
    __syncthreads();   // #A

    // ---- (3) layer 2 -> wT, xT/shT writes ----
    {
        const int ws = wv >> 1;
        const int ebyte = (wv & 1) * 32 + lk * 8;
        unsigned char* bw = smem + W_OFF + ws * 12288;
#pragma unroll
        for (int nt = 0; nt < 12; ++nt) {
            f32x4 acc = {0.f, 0.f, 0.f, 0.f};
#pragma unroll
            for (int kk = 0; kk < 2; ++kk) {
                s16x8 b = *(const s16x8*)(w2t + (nt * 16 + lr) * 64 + kk * 32 + lk * 8);
                acc = __builtin_amdgcn_mfma_f32_16x16x32_bf16(hfrag[kk], b, acc, 0, 0, 0);
            }
            int f = nt * 16 + lr;
            fp16x2 p0 = __builtin_amdgcn_cvt_pkrtz(acc[0] * 0.125f, acc[1] * 0.125f);
            fp16x2 p1 = __builtin_amdgcn_cvt_pkrtz(acc[2] * 0.125f, acc[3] * 0.125f);
            uint2 wval = { __builtin_bit_cast(unsigned, p0), __builtin_bit_cast(unsigned, p1) };
            *(uint2*)(bw + swz(f, ebyte)) = wval;
        }
    }
    {
        unsigned char* bx = smem + X_OFF + hs * 10240;
#pragma unroll
        for (int k = 0; k < 5; ++k) {
            unsigned short u[8];
            *(float4*)u = xg[k];
#pragma unroll
            for (int jj = 0; jj < 8; ++jj) {
                int r = (cgrp * 5 + k) * 8 + jj;
                *(unsigned short*)(bx + swz(r, xe * 2)) = u[jj];
            }
        }
    }
    {
        int e = t >> 2, c = t & 3;
        *(_Float16*)(smem + SH_OFF + (e >> 5) * 256 + swz(c, (e & 31) * 2)) = (_Float16)shv;
    }
    __syncthreads();   // #B

    // ---- (4) phase C ----
    const int nseg = *(const int*)(smem + NSEG_OFF);
    const int eb = lk * 16;

    h8 shreg[4][2];
    unsigned vv[2][4];
#pragma unroll
    for (int ks = 0; ks < 2; ++ks) {
#pragma unroll
        for (int r = 0; r < 4; ++r)
            shreg[r][ks] = rdh8(smem + SH_OFF + ks * 256, r, eb);
        uint4 sv = *(const uint4*)(smem + SID_OFF + ks * 64 + lk * 16);
        vv[ks][0] = sv.x; vv[ks][1] = sv.y; vv[ks][2] = sv.z; vv[ks][3] = sv.w;
    }

    h8 Bv[4][2];
    int fcol[4];
    bool cls3j[4] = {false, false, false, false};
#pragma unroll
    for (int ks = 0; ks < 2; ++ks) {
        const unsigned char* bx = smem + X_OFF + ks * 10240;
        const unsigned char* bw = smem + W_OFF + ks * 12288;
        if (wv == 0) {
#pragma unroll
            for (int jj = 0; jj < 4; ++jj) {
                int col = jj * 16 + lr;
                Bv[jj][ks] = rdh8(bw, col, eb) * rdh8(bx, col, eb);
                fcol[jj] = col;
            }
        } else if (wv == 1) {
#pragma unroll
            for (int jj = 0; jj < 4; ++jj) {
                int col = jj * 16 + lr;
                Bv[jj][ks] = rdh8(bw, 128 + col / 3, eb) * rdh8(bx, 64 + col, eb);
                fcol[jj] = 288 + col;
            }
        } else if (wv == 2) {
#pragma unroll
            for (int jj = 0; jj < 2; ++jj) {
                int col = 64 + jj * 16 + lr;
                Bv[jj][ks] = rdh8(bw, 128 + col / 3, eb) * rdh8(bx, 64 + col, eb);
                fcol[jj] = 288 + col;
            }
#pragma unroll
            for (int jj = 2; jj < 4; ++jj) {
                int col = (jj - 2) * 16 + lr;
                h8 d = rdh8(bx, 64 + 3 * col, eb)     * shreg[1][ks]
                     + rdh8(bx, 64 + 3 * col + 1, eb) * shreg[2][ks]
                     + rdh8(bx, 64 + 3 * col + 2, eb) * shreg[3][ks];
                Bv[jj][ks] = rdh8(bw, 160 + col, eb) * d;
                fcol[jj] = 64 + col;
                cls3j[jj] = true;
            }
        } else {
#pragma unroll
            for (int jj = 0; jj < 4; ++jj) {
                int col = jj * 16 + lr;
                Bv[jj][ks] = rdh8(bw, 64 + col, eb) * rdh8(bx, col, eb);
                fcol[jj] = 96 + 3 * col;
            }
        }
    }

    if (wv != 3) {
        const int npass = (nseg + 15) >> 4;
        for (int p = 0; p < npass; ++p) {
            h8 bm0 = seg_mask(vv[0], (unsigned)(p * 16 + lr));
            h8 bm1 = seg_mask(vv[1], (unsigned)(p * 16 + lr));
            h8 As0 = bm0 * shreg[0][0];
            h8 As1 = bm1 * shreg[0][1];
            const int m0 = p * 16 + lk * 4;
            float* nptr[4]; bool valid[4], atq[4];
#pragma unroll
            for (int q = 0; q < 4; ++q) {
                int sg = m0 + q;
                valid[q] = sg < nseg;
                int node = valid[q] ? s_segnode[sg] : 0;
                nptr[q] = accg + (size_t)node * FEAT;
                atq[q] = (sg == 0) || (sg == nseg - 1);
            }
#pragma unroll
            for (int jj = 0; jj < 4; ++jj) {
                f32x4 acc = {0.f, 0.f, 0.f, 0.f};
                acc = __builtin_amdgcn_mfma_f32_16x16x32_f16(cls3j[jj] ? bm0 : As0, Bv[jj][0], acc, 0, 0, 0);
                acc = __builtin_amdgcn_mfma_f32_16x16x32_f16(cls3j[jj] ? bm1 : As1, Bv[jj][1], acc, 0, 0, 0);
                const float sc = cls3j[jj] ? INV_SQRT3 : 1.f;
#pragma unroll
                for (int q = 0; q < 4; ++q) {
                    if (valid[q]) {
                        float v = acc[q] * sc;
                        float* a = nptr[q] + fcol[jj];
                        if (atq[q]) atomicAdd(a, v); else *a = v;
                    }
                }
            }
        }
    } else {
        const int npass = (3 * nseg + 15) >> 4;
        for (int p = 0; p < npass; ++p) {
            int m = p * 16 + lr;
            int sgA = m / 3, i3A = m - 3 * sgA;
            h8 mk0 = seg_mask(vv[0], (unsigned)sgA);
            h8 mk1 = seg_mask(vv[1], (unsigned)sgA);
            h8 A0 = mk0 * ((i3A == 0) ? shreg[1][0] : (i3A == 1) ? shreg[2][0] : shreg[3][0]);
            h8 A1 = mk1 * ((i3A == 0) ? shreg[1][1] : (i3A == 1) ? shreg[2][1] : shreg[3][1]);
            int m0 = p * 16 + lk * 4;
            int sgq = m0 / 3, rq = m0 - 3 * sgq;
            float* nptr[4]; int i3q[4]; bool valid[4], atq[4];
#pragma unroll
            for (int q = 0; q < 4; ++q) {
                valid[q] = sgq < nseg;
                int node = valid[q] ? s_segnode[sgq] : 0;
                nptr[q] = accg + (size_t)node * FEAT;
                i3q[q] = rq;
                atq[q] = (sgq == 0) || (sgq == nseg - 1);
                if (++rq == 3) { rq = 0; ++sgq; }
            }
#pragma unroll
            for (int jj = 0; jj < 4; ++jj) {
                f32x4 acc = {0.f, 0.f, 0.f, 0.f};
                acc = __builtin_amdgcn_mfma_f32_16x16x32_f16(A0, Bv[jj][0], acc, 0, 0, 0);
                acc = __builtin_amdgcn_mfma_f32_16x16x32_f16(A1, Bv[jj][1], acc, 0, 0, 0);
#pragma unroll
                for (int q = 0; q < 4; ++q) {
                    if (valid[q]) {
                        float* a = nptr[q] + fcol[jj] + i3q[q];
                        if (atq[q]) atomicAdd(a, acc[q]); else *a = acc[q];
                    }
                }
            }
        }
    }
}

// ---------------- node epilogue (MFMA) ----------------

static __device__ __forceinline__ s16x8 frag_c8(const float* p, float s) {
    float4 u = *(const float4*)p, v = *(const float4*)(p + 4);
    s16x8 a;
    a[0] = f2bf(u.x * s); a[1] = f2bf(u.y * s); a[2] = f2bf(u.z * s); a[3] = f2bf(u.w * s);
    a[4] = f2bf(v.x * s); a[5] = f2bf(v.y * s); a[6] = f2bf(v.z * s); a[7] = f2bf(v.w * s);
    return a;
}

__global__ __launch_bounds__(256) void node_kernel(
    const float* __restrict__ x,
    const float* __restrict__ accg,
    const int*   __restrict__ cnt,
    const unsigned short* __restrict__ wscs_t,
    const unsigned short* __restrict__ wscv_t,
    const unsigned short* __restrict__ wlins_t,
    const unsigned short* __restrict__ wlinv_t,
    const float* __restrict__ w_alpha,
    float* __restrict__ out)
{
    const int t = threadIdx.x;
    const int wv = t >> 6, l = t & 63;
    const int lr = l & 15, lk = l >> 4;
    const int n_base = blockIdx.x * 64 + wv * 16;
    const int nrow = n_base + lr;
    const int nclamp = min(nrow, N_NODES - 1);

    const float* mrow = accg + (size_t)nclamp * FEAT;
    const float* xrow = x + (size_t)nclamp * D_IN;
    const float rinv = 1.f / (float)max(cnt[nclamp], 1);

    s16x8 ax[2], ams[3], axv[3], amv[3][3];
#pragma unroll
    for (int kk = 0; kk < 2; ++kk) ax[kk] = frag_c8(xrow + kk * 32 + lk * 8, 1.f);
#pragma unroll
    for (int kk = 0; kk < 3; ++kk) ams[kk] = frag_c8(mrow + kk * 32 + lk * 8, rinv);
    {
        float xb[24];
        const float4* p = (const float4*)(xrow + 64 + 24 * lk);
#pragma unroll
        for (int q = 0; q < 6; ++q) ((float4*)xb)[q] = p[q];
#pragma unroll
        for (int i = 0; i < 3; ++i) {
            s16x8 a;
#pragma unroll
            for (int j = 0; j < 8; ++j) a[j] = f2bf(xb[3 * j + i]);
            axv[i] = a;
        }
    }
#pragma unroll
    for (int kk = 0; kk < 3; ++kk) {
        float mb[24];
        const float4* p = (const float4*)(mrow + 96 + 96 * kk + 24 * lk);
#pragma unroll
        for (int q = 0; q < 6; ++q) ((float4*)mb)[q] = p[q];
#pragma unroll
        for (int i = 0; i < 3; ++i) {
            s16x8 a;
#pragma unroll
            for (int j = 0; j < 8; ++j) a[j] = f2bf(mb[3 * j + i] * rinv);
            amv[i][kk] = a;
        }
    }

    float ap = 0.f;
    {
        float ab[24];
        const float4* p = (const float4*)(mrow + 24 * lk);
#pragma unroll
        for (int q = 0; q < 6; ++q) ((float4*)ab)[q] = p[q];
#pragma unroll
        for (int j = 0; j < 24; ++j) ap += ab[j] * rinv * w_alpha[lk * 24 + j];
    }
    ap += __shfl_xor(ap, 16);
    ap += __shfl_xor(ap, 32);
    const float alphav = ap * RSQRT96;

    f32x4 accA[4], accL[4];
#pragma unroll
    for (int nt = 0; nt < 4; ++nt) { accA[nt] = (f32x4){0,0,0,0}; accL[nt] = (f32x4){0,0,0,0}; }
#pragma unroll
    for (int nt = 0; nt < 4; ++nt) {
#pragma unroll
        for (int kk = 0; kk < 2; ++kk) {
            s16x8 b = *(const s16x8*)(wscs_t + (nt * 16 + lr) * 64 + kk * 32 + lk * 8);
            accA[nt] = __builtin_amdgcn_mfma_f32_16x16x32_bf16(ax[kk], b, accA[nt], 0, 0, 0);
        }
#pragma unroll
        for (int kk = 0; kk < 3; ++kk) {
            s16x8 b = *(const s16x8*)(wlins_t + (nt * 16 + lr) * 96 + kk * 32 + lk * 8);
            accL[nt] = __builtin_amdgcn_mfma_f32_16x16x32_bf16(ams[kk], b, accL[nt], 0, 0, 0);
        }
    }
    f32x4 accVs[3][2], accVl[3][2];
#pragma unroll
    for (int i = 0; i < 3; ++i)
#pragma unroll
        for (int nt = 0; nt < 2; ++nt) { accVs[i][nt] = (f32x4){0,0,0,0}; accVl[i][nt] = (f32x4){0,0,0,0}; }
#pragma unroll
    for (int i = 0; i < 3; ++i) {
#pragma unroll
        for (int nt = 0; nt < 2; ++nt) {
            s16x8 b = *(const s16x8*)(wscv_t + (nt * 16 + lr) * 32 + lk * 8);
            accVs[i][nt] = __builtin_amdgcn_mfma_f32_16x16x32_bf16(axv[i], b, accVs[i][nt], 0, 0, 0);
#pragma unroll
            for (int kk = 0; kk < 3; ++kk) {
                s16x8 b2 = *(const s16x8*)(wlinv_t + (nt * 16 + lr) * 96 + kk * 32 + lk * 8);
                accVl[i][nt] = __builtin_amdgcn_mfma_f32_16x16x32_bf16(amv[i][kk], b2, accVl[i][nt], 0, 0, 0);
            }
        }
    }

#pragma unroll
    for (int q = 0; q < 4; ++q) {
        int row = lk * 4 + q;
        float ar = __shfl(alphav, row);
        int n = n_base + row;
        bool ok = (n < N_NODES);
        float* orow = out + (size_t)n * 160;
#pragma unroll
        for (int nt = 0; nt < 4; ++nt) {
            float vout = accA[nt][q] * 0.125f + ar * accL[nt][q] * RSQRT96;
            if (ok) orow[nt * 16 + lr] = vout;
        }
#pragma unroll
        for (int i = 0; i < 3; ++i)
#pragma unroll
            for (int nt = 0; nt < 2; ++nt) {
                float vout = accVs[i][nt][q] * RSQRT32 + ar * accVl[i][nt][q] * RSQRT96;
                if (ok) orow[64 + 3 * (nt * 16 + lr) + i] = vout;
            }
    }
}

// ---------------- launch ----------------

extern "C" void kernel_launch(void* const* d_in, const int* in_sizes, int n_in,
                              void* d_out, int out_size, void* d_ws, size_t ws_size,
                              hipStream_t stream) {
    const float* x        = (const float*)d_in[0];
    const float* es       = (const float*)d_in[1];
    const float* sh       = (const float*)d_in[2];
    const int*   eidx     = (const int*)d_in[3];
    const float* w_fc1    = (const float*)d_in[4];
    const float* w_fc2    = (const float*)d_in[5];
    const float* w_sc_s   = (const float*)d_in[6];
    const float* w_sc_v   = (const float*)d_in[7];
    const float* w_lin_s  = (const float*)d_in[8];
    const float* w_lin_v  = (const float*)d_in[9];
    const float* w_alpha  = (const float*)d_in[10];
    float* out = (float*)d_out;

    float* accg       = (float*)d_ws;
    int*   cnt        = (int*)(accg + (size_t)N_NODES * FEAT);
    int*   fill       = cnt + N_NODES;
    int*   sorted_eid = fill + N_NODES;
    int*   sorted_src = sorted_eid + N_EDGES;
    int*   sorted_dst = sorted_src + N_EDGES;
    unsigned short* w1t     = (unsigned short*)(sorted_dst + N_EDGES);
    unsigned short* w2t     = w1t + 64 * 64;
    unsigned short* wscs_t  = w2t + 192 * 64;
    unsigned short* wscv_t  = wscs_t + 64 * 64;
    unsigned short* wlins_t = wscv_t + 32 * 32;
    unsigned short* wlinv_t = wlins_t + 64 * 96;
    int* bsum = (int*)(wlinv_t + 32 * 96);
    size_t base_bytes = (size_t)((unsigned char*)(bsum + SCAN_NB) - (unsigned char*)d_ws);
    base_bytes = (base_bytes + 15) & ~(size_t)15;
    unsigned short* x16 = (unsigned short*)((unsigned char*)d_ws + base_bytes);   // N*160 f16

    (void)hipMemsetAsync(d_ws, 0, ((size_t)N_NODES * FEAT + N_NODES) * 4, stream);
    hipLaunchKernelGGL(hist_prep_kernel, dim3(HIST_NB + 48 + XCONV_NB), dim3(256), 0, stream,
                       eidx, cnt, w_fc1, w_fc2, w_sc_s, w_sc_v, w_lin_s, w_lin_v,
                       x, x16, w1t, w2t, wscs_t, wscv_t, wlins_t, wlinv_t);
    hipLaunchKernelGGL(scanA_kernel, dim3(SCAN_NB), dim3(256), 0, stream, cnt, bsum);
    hipLaunchKernelGGL(scanC_kernel, dim3(SCAN_NB), dim3(256), 0, stream, cnt, bsum, fill);
    hipLaunchKernelGGL(scatter_ids_kernel, dim3((N_EDGES + 255) / 256), dim3(256), 0, stream,
                       eidx, fill, sorted_eid, sorted_src, sorted_dst);
    hipLaunchKernelGGL(edge_kernel, dim3(NWG_EDGE), dim3(256), 0, stream,
                       x16, es, sh, sorted_eid, sorted_src, sorted_dst, w1t, w2t, accg);
    hipLaunchKernelGGL(node_kernel, dim3((N_NODES + 63) / 64), dim3(256), 0, stream,
                       x, accg, cnt, wscs_t, wscv_t, wlins_t, wlinv_t, w_alpha, out);
}